// Round 9
// baseline (837.491 us; speedup 1.0000x reference)
//
#include <hip/hip_runtime.h>
#include <math.h>

#define TOKENS 16384
#define HIDDEN 2048
#define BM 256
#define BN 256
#define BK 32
#define NT (HIDDEN / BK)   // 64 K-tiles

typedef __attribute__((ext_vector_type(4))) float f32x4;
typedef __attribute__((ext_vector_type(8))) short s16x8;

__device__ __forceinline__ unsigned short f2bf(float f) {
  unsigned int u = __float_as_uint(f);
  u += 0x7fffu + ((u >> 16) & 1u);   // round-to-nearest-even
  return (unsigned short)(u >> 16);
}

// tanh-approx GELU via raw v_exp_f32 + v_rcp_f32; |err vs erf-gelu| ~1e-3.
__device__ __forceinline__ float fast_gelu(float y) {
  float t = y * fmaf(y * y, 0.044715f, 1.0f);
  float e = __builtin_amdgcn_exp2f(-2.3022082f * t);
  return y * __builtin_amdgcn_rcpf(1.0f + e);
}

// ---------------- kernel 0: W fp32 -> bf16 ----------------
__global__ __launch_bounds__(256) void wconv_kernel(const float* __restrict__ W,
                                                    unsigned short* __restrict__ Wb) {
  const int n4 = (HIDDEN * HIDDEN) / 4;
  for (int i = blockIdx.x * 256 + threadIdx.x; i < n4; i += gridDim.x * 256) {
    float4 v = *(const float4*)(W + (size_t)i * 4);
    ushort4 o;
    o.x = f2bf(v.x); o.y = f2bf(v.y); o.z = f2bf(v.z); o.w = f2bf(v.w);
    *(ushort4*)(Wb + (size_t)i * 4) = o;
  }
}

// ---------------- kernel 1: LayerNorm fp32 -> bf16, one block per row ----------------
__global__ __launch_bounds__(256) void ln_kernel(const float* __restrict__ x,
                                                 const float* __restrict__ gamma,
                                                 const float* __restrict__ beta,
                                                 unsigned short* __restrict__ xn) {
  const int row = blockIdx.x;
  const int t = threadIdx.x;
  const int wave = t >> 6, lane = t & 63;
  const float* xr = x + (size_t)row * HIDDEN + t * 8;
  float4 v0 = *(const float4*)(xr);
  float4 v1 = *(const float4*)(xr + 4);
  float xv[8] = {v0.x, v0.y, v0.z, v0.w, v1.x, v1.y, v1.z, v1.w};

  float s = 0.f, ss = 0.f;
#pragma unroll
  for (int j = 0; j < 8; ++j) { s += xv[j]; ss = fmaf(xv[j], xv[j], ss); }

#pragma unroll
  for (int off = 32; off > 0; off >>= 1) {
    s += __shfl_xor(s, off, 64);
    ss += __shfl_xor(ss, off, 64);
  }
  __shared__ float rs[4], rss[4];
  if (lane == 0) { rs[wave] = s; rss[wave] = ss; }
  __syncthreads();
  s = rs[0] + rs[1] + rs[2] + rs[3];
  ss = rss[0] + rss[1] + rss[2] + rss[3];

  const float mean = s * (1.0f / HIDDEN);
  const float var = ss * (1.0f / HIDDEN) - mean * mean;
  const float rstd = rsqrtf(var + 1e-5f);

  float4 g0 = *(const float4*)(gamma + t * 8);
  float4 g1 = *(const float4*)(gamma + t * 8 + 4);
  float4 b0 = *(const float4*)(beta + t * 8);
  float4 b1 = *(const float4*)(beta + t * 8 + 4);
  float gv[8] = {g0.x, g0.y, g0.z, g0.w, g1.x, g1.y, g1.z, g1.w};
  float bv[8] = {b0.x, b0.y, b0.z, b0.w, b1.x, b1.y, b1.z, b1.w};

  union { unsigned short h[8]; uint4 q; } pk;
#pragma unroll
  for (int j = 0; j < 8; ++j)
    pk.h[j] = f2bf((xv[j] - mean) * rstd * gv[j] + bv[j]);
  *(uint4*)(xn + (size_t)row * HIDDEN + t * 8) = pk.q;
}

// ---------------- kernel 2: 256x256 BK=32 4-phase bf16 GEMM, 2 blocks/CU --------------
// A[M,K] * B[N,K]^T. 512 threads = 8 waves (2M x 4N), per-wave output 128x64.
// LDS 64 KiB (2 blocks/CU co-resident): per buf, A[256][32] + B[256][32] bf16,
// row = 64 B (4 x 16B slots). Swizzle: slot ^= (row>>1)&3 on gather source AND ds_read.
// Stage quantum = 8 KB = one 512-thread GLOAD sweep = one 128-row half of A or B.
//
// READ liveness per tile t from buf: A read in p0 (rows 0-63/half) and p2 (64-127);
// B read in p0 (qn0), p1 (qn1), p3 (qn0 AGAIN — snake re-read). Therefore:
//   p0: stage B(t+1)->buf^1 h0   [B of buf^1 fully read at end of t-1's p3]
//   p1: stage B(t+1)->buf^1 h1
//   p2: NO stage                 [A of buf still being read in p2 itself]
//   p3: stage A(t+2)->buf h0,h1  [A of buf fully read after p2's closing barrier]
//       + vmcnt(2): outstanding = the two A(t+2) calls => B(t+1) proven landed.
// Prologue: A(0)x2,B(0)x2 -> buf0; A(1)x2 -> buf1; vmcnt(2).
// XCD swizzle: round-3 form (private M-slab per XCD). setprio around MFMA.

#define GLOAD(gp, lp) __builtin_amdgcn_global_load_lds( \
    (const __attribute__((address_space(1))) unsigned int*)(gp), \
    (__attribute__((address_space(3))) unsigned int*)(lp), 16, 0, 0)

__global__ __launch_bounds__(512, 4) void gemm_kernel(const unsigned short* __restrict__ A,
                                                      const unsigned short* __restrict__ B,
                                                      const float* __restrict__ bias,
                                                      float* __restrict__ out) {
  __shared__ __attribute__((aligned(16))) char lds[65536];

  const int tid = threadIdx.x;
  const int lane = tid & 63;
  const int wave = tid >> 6;
  const int fr = lane & 15, hi = lane >> 4;

  // XCD-aware swizzle (round-3 form): each XCD owns a private contiguous M-slab.
  const int wg = blockIdx.x;
  const int swz = (wg & 7) * 64 + (wg >> 3);
  const int tm = swz >> 3, tn = swz & 7;   // 64 M-tiles x 8 N-tiles
  const int row0 = tm * BM, col0 = tn * BN;

  const int wmi = wave >> 2;        // wave M index (0..1)
  const int wni = wave & 3;         // wave N index (0..3)
  const int hB = wni >> 1, gB = wni & 1;

  // ---- staging geometry: lane tid -> row rho=tid>>2 (0..127) of a 128-row half,
  // 16B slot sig=tid&3; source k-slot pre-swizzled so reads can XOR-deswizzle.
  const int rho = tid >> 2, sig = tid & 3;
  const int colgrp = ((sig ^ ((rho >> 1) & 3)) << 3);          // k-element offset
  const unsigned short* Ap = A + (size_t)(row0 + rho) * HIDDEN + colgrp;
  const unsigned short* Bp = B + (size_t)(col0 + rho) * HIDDEN + colgrp;

  // ---- ds_read per-lane constants: row*64 + swizzled 16B slot (slot = hi, 0..3) ----
  const int slotb = ((hi ^ ((fr >> 1) & 3)) << 4);
  const int aRow = fr * 64 + slotb;                 // + qm*4096 + mi*1024
  const int bRow = gB * 4096 + fr * 64 + slotb;     // + qn*2048 + nj*1024

  auto stageA = [&](int tt, int bufd, int h) {      // one call: A rows h*128..h*128+127
    const int tc = tt < NT ? tt : NT - 1;
    GLOAD(Ap + (size_t)(h << 7) * HIDDEN + tc * BK,
          lds + (bufd << 14) + (h << 13) + tid * 16);
  };
  auto stageB = [&](int tt, int bufd, int h) {      // one call: B rows h*128..h*128+127
    const int tc = tt < NT ? tt : NT - 1;
    GLOAD(Bp + (size_t)(h << 7) * HIDDEN + tc * BK,
          lds + 32768 + (bufd << 14) + (h << 13) + tid * 16);
  };

  f32x4 acc[2][4][4] = {};
  s16x8 a[4], b[2];

  // ---- prologue: tile0 all 4 halves -> buf0; tile1 A halves -> buf1; vmcnt(2) ----
  stageA(0, 0, 0); stageA(0, 0, 1); stageB(0, 0, 0); stageB(0, 0, 1);
  stageA(1, 1, 0); stageA(1, 1, 1);
  asm volatile("s_waitcnt vmcnt(2)" ::: "memory");   // tile0 landed; A(1)x2 in flight
  __builtin_amdgcn_s_barrier();

  for (int t = 0; t < NT; ++t) {
    const int buf = t & 1;
    const char* Abase = lds + (buf << 14) + (wmi << 13);          // wave's A half
    const char* Bbase = lds + 32768 + (buf << 14) + (hB << 13);   // wave's B half

    // ===== p0: (qm=0, qn=0) — 4 A + 2 B reads; stage B(t+1) h0 -> buf^1 =====
#pragma unroll
    for (int mi = 0; mi < 4; ++mi)
      a[mi] = *(const s16x8*)(Abase + mi * 1024 + aRow);
#pragma unroll
    for (int nj = 0; nj < 2; ++nj)
      b[nj] = *(const s16x8*)(Bbase + nj * 1024 + bRow);
    stageB(t + 1, buf ^ 1, 0);
    asm volatile("s_waitcnt lgkmcnt(4)" ::: "memory");
    __builtin_amdgcn_s_barrier();
    asm volatile("s_waitcnt lgkmcnt(0)" ::: "memory");
    __builtin_amdgcn_s_setprio(1);
#pragma unroll
    for (int mi = 0; mi < 4; ++mi)
#pragma unroll
      for (int nj = 0; nj < 2; ++nj)
        acc[0][mi][nj] = __builtin_amdgcn_mfma_f32_16x16x32_bf16(a[mi], b[nj], acc[0][mi][nj], 0, 0, 0);
    __builtin_amdgcn_s_setprio(0);
    __builtin_amdgcn_s_barrier();

    // ===== p1: (qm=0, qn=1) — reuse a; 2 B reads; stage B(t+1) h1 -> buf^1 =====
#pragma unroll
    for (int nj = 0; nj < 2; ++nj)
      b[nj] = *(const s16x8*)(Bbase + 2048 + nj * 1024 + bRow);
    stageB(t + 1, buf ^ 1, 1);
    __builtin_amdgcn_s_barrier();
    asm volatile("s_waitcnt lgkmcnt(0)" ::: "memory");
    __builtin_amdgcn_s_setprio(1);
#pragma unroll
    for (int mi = 0; mi < 4; ++mi)
#pragma unroll
      for (int nj = 0; nj < 2; ++nj)
        acc[0][mi][2 + nj] = __builtin_amdgcn_mfma_f32_16x16x32_bf16(a[mi], b[nj], acc[0][mi][2 + nj], 0, 0, 0);
    __builtin_amdgcn_s_setprio(0);
    __builtin_amdgcn_s_barrier();

    // ===== p2: (qm=1, qn=1) — reuse b; 4 A reads; NO stage =====
#pragma unroll
    for (int mi = 0; mi < 4; ++mi)
      a[mi] = *(const s16x8*)(Abase + 4096 + mi * 1024 + aRow);
    __builtin_amdgcn_s_barrier();
    asm volatile("s_waitcnt lgkmcnt(0)" ::: "memory");
    __builtin_amdgcn_s_setprio(1);
#pragma unroll
    for (int mi = 0; mi < 4; ++mi)
#pragma unroll
      for (int nj = 0; nj < 2; ++nj)
        acc[1][mi][2 + nj] = __builtin_amdgcn_mfma_f32_16x16x32_bf16(a[mi], b[nj], acc[1][mi][2 + nj], 0, 0, 0);
    __builtin_amdgcn_s_setprio(0);
    __builtin_amdgcn_s_barrier();

    // ===== p3: (qm=1, qn=0) — reuse a; 2 B reads; stage A(t+2) h0,h1 -> buf =====
#pragma unroll
    for (int nj = 0; nj < 2; ++nj)
      b[nj] = *(const s16x8*)(Bbase + nj * 1024 + bRow);
    stageA(t + 2, buf, 0);
    stageA(t + 2, buf, 1);
    asm volatile("s_waitcnt vmcnt(2)" ::: "memory");   // only A(t+2)x2 in flight; B(t+1) landed
    __builtin_amdgcn_s_barrier();
    asm volatile("s_waitcnt lgkmcnt(0)" ::: "memory");
    __builtin_amdgcn_s_setprio(1);
#pragma unroll
    for (int mi = 0; mi < 4; ++mi)
#pragma unroll
      for (int nj = 0; nj < 2; ++nj)
        acc[1][mi][nj] = __builtin_amdgcn_mfma_f32_16x16x32_bf16(a[mi], b[nj], acc[1][mi][nj], 0, 0, 0);
    __builtin_amdgcn_s_setprio(0);
    __builtin_amdgcn_s_barrier();
  }

  asm volatile("s_waitcnt vmcnt(0)" ::: "memory");   // drain clamped tail prefetches

  // ---- epilogue: bias + fast GELU, fp32 store (16x16 C/D mapping, m89/m91) ----
  float bcol[4];
#pragma unroll
  for (int ni = 0; ni < 4; ++ni)
    bcol[ni] = bias[col0 + (wni << 6) + ni * 16 + fr];

#pragma unroll
  for (int qm = 0; qm < 2; ++qm)
#pragma unroll
    for (int mi = 0; mi < 4; ++mi)
#pragma unroll
      for (int ni = 0; ni < 4; ++ni) {
        const int c = col0 + (wni << 6) + ni * 16 + fr;
#pragma unroll
        for (int j = 0; j < 4; ++j) {
          const int r = row0 + wmi * 128 + qm * 64 + mi * 16 + hi * 4 + j;
          float y = acc[qm][mi][ni][j] + bcol[ni];
          out[(size_t)r * HIDDEN + c] = fast_gelu(y);
        }
      }
}

extern "C" void kernel_launch(void* const* d_in, const int* in_sizes, int n_in,
                              void* d_out, int out_size, void* d_ws, size_t ws_size,
                              hipStream_t stream) {
  const float* x     = (const float*)d_in[0];
  const float* gamma = (const float*)d_in[1];
  const float* beta  = (const float*)d_in[2];
  const float* W     = (const float*)d_in[3];
  const float* bias  = (const float*)d_in[4];
  float* out = (float*)d_out;

  unsigned short* xn = (unsigned short*)d_ws;
  unsigned short* wb = (unsigned short*)((char*)d_ws + (size_t)TOKENS * HIDDEN * 2);

  hipLaunchKernelGGL(wconv_kernel, dim3(1024), dim3(256), 0, stream, W, wb);
  hipLaunchKernelGGL(ln_kernel, dim3(TOKENS), dim3(256), 0, stream, x, gamma, beta, xn);
  hipLaunchKernelGGL(gemm_kernel, dim3((TOKENS / BM) * (HIDDEN / BN)), dim3(512), 0, stream,
                     xn, wb, bias, out);
}

// Round 10
// 186.896 us; speedup vs baseline: 4.4810x; 4.4810x over previous
//
#include <hip/hip_runtime.h>
#include <math.h>

#define TOKENS 16384
#define HIDDEN 2048
#define BM 256
#define BN 256
#define BK 32
#define NT (HIDDEN / BK)   // 64 K-tiles

typedef __attribute__((ext_vector_type(4))) float f32x4;
typedef __attribute__((ext_vector_type(8))) short s16x8;

__device__ __forceinline__ unsigned short f2bf(float f) {
  unsigned int u = __float_as_uint(f);
  u += 0x7fffu + ((u >> 16) & 1u);   // round-to-nearest-even
  return (unsigned short)(u >> 16);
}

// tanh-approx GELU via raw v_exp_f32 + v_rcp_f32; |err vs erf-gelu| ~1e-3.
__device__ __forceinline__ float fast_gelu(float y) {
  float t = y * fmaf(y * y, 0.044715f, 1.0f);
  float e = __builtin_amdgcn_exp2f(-2.3022082f * t);
  return y * __builtin_amdgcn_rcpf(1.0f + e);
}

// ---------------- kernel 0: W fp32 -> bf16 ----------------
__global__ __launch_bounds__(256) void wconv_kernel(const float* __restrict__ W,
                                                    unsigned short* __restrict__ Wb) {
  const int n4 = (HIDDEN * HIDDEN) / 4;
  for (int i = blockIdx.x * 256 + threadIdx.x; i < n4; i += gridDim.x * 256) {
    float4 v = *(const float4*)(W + (size_t)i * 4);
    ushort4 o;
    o.x = f2bf(v.x); o.y = f2bf(v.y); o.z = f2bf(v.z); o.w = f2bf(v.w);
    *(ushort4*)(Wb + (size_t)i * 4) = o;
  }
}

// ---------------- kernel 1: LayerNorm fp32 -> bf16, one block per row ----------------
__global__ __launch_bounds__(256) void ln_kernel(const float* __restrict__ x,
                                                 const float* __restrict__ gamma,
                                                 const float* __restrict__ beta,
                                                 unsigned short* __restrict__ xn) {
  const int row = blockIdx.x;
  const int t = threadIdx.x;
  const int wave = t >> 6, lane = t & 63;
  const float* xr = x + (size_t)row * HIDDEN + t * 8;
  float4 v0 = *(const float4*)(xr);
  float4 v1 = *(const float4*)(xr + 4);
  float xv[8] = {v0.x, v0.y, v0.z, v0.w, v1.x, v1.y, v1.z, v1.w};

  float s = 0.f, ss = 0.f;
#pragma unroll
  for (int j = 0; j < 8; ++j) { s += xv[j]; ss = fmaf(xv[j], xv[j], ss); }

#pragma unroll
  for (int off = 32; off > 0; off >>= 1) {
    s += __shfl_xor(s, off, 64);
    ss += __shfl_xor(ss, off, 64);
  }
  __shared__ float rs[4], rss[4];
  if (lane == 0) { rs[wave] = s; rss[wave] = ss; }
  __syncthreads();
  s = rs[0] + rs[1] + rs[2] + rs[3];
  ss = rss[0] + rss[1] + rss[2] + rss[3];

  const float mean = s * (1.0f / HIDDEN);
  const float var = ss * (1.0f / HIDDEN) - mean * mean;
  const float rstd = rsqrtf(var + 1e-5f);

  float4 g0 = *(const float4*)(gamma + t * 8);
  float4 g1 = *(const float4*)(gamma + t * 8 + 4);
  float4 b0 = *(const float4*)(beta + t * 8);
  float4 b1 = *(const float4*)(beta + t * 8 + 4);
  float gv[8] = {g0.x, g0.y, g0.z, g0.w, g1.x, g1.y, g1.z, g1.w};
  float bv[8] = {b0.x, b0.y, b0.z, b0.w, b1.x, b1.y, b1.z, b1.w};

  union { unsigned short h[8]; uint4 q; } pk;
#pragma unroll
  for (int j = 0; j < 8; ++j)
    pk.h[j] = f2bf((xv[j] - mean) * rstd * gv[j] + bv[j]);
  *(uint4*)(xn + (size_t)row * HIDDEN + t * 8) = pk.q;
}

// ---------------- kernel 2: 256x256 BK=32 4-phase bf16 GEMM, 2 blocks/CU --------------
// A[M,K] * B[N,K]^T. 512 threads = 8 waves (2M x 4N), per-wave output 128x64.
// LDS 64 KiB (2 blocks/CU co-resident): per buf, A[256][32] + B[256][32] bf16,
// row = 64 B (4 x 16B slots). Swizzle: slot ^= (row>>1)&3 on gather source AND ds_read.
// Stage quantum = 8 KB = one 512-thread GLOAD sweep = one 128-row half of A or B.
//
// NOTE on launch bounds: NO min-occupancy arg. (512,4) made hipcc clamp to 64 VGPR ->
// the 128-f32 accumulator spilled to scratch (round-9: 4.2 GB HBM traffic, MfmaUtil 2%).
// Natural allocation ~104-112 VGPR <= 128 -> 4 waves/SIMD -> 2 blocks/CU, no spills.
//
// READ liveness per tile t from buf: A read in p0 (rows 0-63/half) and p2 (64-127);
// B read in p0 (qn0), p1 (qn1), p3 (qn0 AGAIN — snake re-read). Therefore:
//   p0: stage B(t+1)->buf^1 h0   [B of buf^1 fully read at end of t-1's p3]
//   p1: stage B(t+1)->buf^1 h1
//   p2: NO stage                 [A of buf still being read in p2 itself]
//   p3: stage A(t+2)->buf h0,h1  [A of buf fully read after p2's closing barrier]
//       + vmcnt(2): outstanding = the two A(t+2) calls => B(t+1) proven landed.
// Prologue: A(0)x2,B(0)x2 -> buf0; A(1)x2 -> buf1; vmcnt(2).
// XCD swizzle: round-3 form (private M-slab per XCD). setprio around MFMA.

#define GLOAD(gp, lp) __builtin_amdgcn_global_load_lds( \
    (const __attribute__((address_space(1))) unsigned int*)(gp), \
    (__attribute__((address_space(3))) unsigned int*)(lp), 16, 0, 0)

__global__ __launch_bounds__(512) void gemm_kernel(const unsigned short* __restrict__ A,
                                                   const unsigned short* __restrict__ B,
                                                   const float* __restrict__ bias,
                                                   float* __restrict__ out) {
  __shared__ __attribute__((aligned(16))) char lds[65536];

  const int tid = threadIdx.x;
  const int lane = tid & 63;
  const int wave = tid >> 6;
  const int fr = lane & 15, hi = lane >> 4;

  // XCD-aware swizzle (round-3 form): each XCD owns a private contiguous M-slab.
  const int wg = blockIdx.x;
  const int swz = (wg & 7) * 64 + (wg >> 3);
  const int tm = swz >> 3, tn = swz & 7;   // 64 M-tiles x 8 N-tiles
  const int row0 = tm * BM, col0 = tn * BN;

  const int wmi = wave >> 2;        // wave M index (0..1)
  const int wni = wave & 3;         // wave N index (0..3)
  const int hB = wni >> 1, gB = wni & 1;

  // ---- staging geometry: lane tid -> row rho=tid>>2 (0..127) of a 128-row half,
  // 16B slot sig=tid&3; source k-slot pre-swizzled so reads can XOR-deswizzle.
  const int rho = tid >> 2, sig = tid & 3;
  const int colgrp = ((sig ^ ((rho >> 1) & 3)) << 3);          // k-element offset
  const unsigned short* Ap = A + (size_t)(row0 + rho) * HIDDEN + colgrp;
  const unsigned short* Bp = B + (size_t)(col0 + rho) * HIDDEN + colgrp;

  // ---- ds_read per-lane constants: row*64 + swizzled 16B slot (slot = hi, 0..3) ----
  const int slotb = ((hi ^ ((fr >> 1) & 3)) << 4);
  const int aRow = fr * 64 + slotb;                 // + qm*4096 + mi*1024
  const int bRow = gB * 4096 + fr * 64 + slotb;     // + qn*2048 + nj*1024

  auto stageA = [&](int tt, int bufd, int h) {      // one call: A rows h*128..h*128+127
    const int tc = tt < NT ? tt : NT - 1;
    GLOAD(Ap + (size_t)(h << 7) * HIDDEN + tc * BK,
          lds + (bufd << 14) + (h << 13) + tid * 16);
  };
  auto stageB = [&](int tt, int bufd, int h) {      // one call: B rows h*128..h*128+127
    const int tc = tt < NT ? tt : NT - 1;
    GLOAD(Bp + (size_t)(h << 7) * HIDDEN + tc * BK,
          lds + 32768 + (bufd << 14) + (h << 13) + tid * 16);
  };

  f32x4 acc[2][4][4] = {};
  s16x8 a[4], b[2];

  // ---- prologue: tile0 all 4 halves -> buf0; tile1 A halves -> buf1; vmcnt(2) ----
  stageA(0, 0, 0); stageA(0, 0, 1); stageB(0, 0, 0); stageB(0, 0, 1);
  stageA(1, 1, 0); stageA(1, 1, 1);
  asm volatile("s_waitcnt vmcnt(2)" ::: "memory");   // tile0 landed; A(1)x2 in flight
  __builtin_amdgcn_s_barrier();

  for (int t = 0; t < NT; ++t) {
    const int buf = t & 1;
    const char* Abase = lds + (buf << 14) + (wmi << 13);          // wave's A half
    const char* Bbase = lds + 32768 + (buf << 14) + (hB << 13);   // wave's B half

    // ===== p0: (qm=0, qn=0) — 4 A + 2 B reads; stage B(t+1) h0 -> buf^1 =====
#pragma unroll
    for (int mi = 0; mi < 4; ++mi)
      a[mi] = *(const s16x8*)(Abase + mi * 1024 + aRow);
#pragma unroll
    for (int nj = 0; nj < 2; ++nj)
      b[nj] = *(const s16x8*)(Bbase + nj * 1024 + bRow);
    stageB(t + 1, buf ^ 1, 0);
    asm volatile("s_waitcnt lgkmcnt(4)" ::: "memory");
    __builtin_amdgcn_s_barrier();
    asm volatile("s_waitcnt lgkmcnt(0)" ::: "memory");
    __builtin_amdgcn_s_setprio(1);
#pragma unroll
    for (int mi = 0; mi < 4; ++mi)
#pragma unroll
      for (int nj = 0; nj < 2; ++nj)
        acc[0][mi][nj] = __builtin_amdgcn_mfma_f32_16x16x32_bf16(a[mi], b[nj], acc[0][mi][nj], 0, 0, 0);
    __builtin_amdgcn_s_setprio(0);
    __builtin_amdgcn_s_barrier();

    // ===== p1: (qm=0, qn=1) — reuse a; 2 B reads; stage B(t+1) h1 -> buf^1 =====
#pragma unroll
    for (int nj = 0; nj < 2; ++nj)
      b[nj] = *(const s16x8*)(Bbase + 2048 + nj * 1024 + bRow);
    stageB(t + 1, buf ^ 1, 1);
    __builtin_amdgcn_s_barrier();
    asm volatile("s_waitcnt lgkmcnt(0)" ::: "memory");
    __builtin_amdgcn_s_setprio(1);
#pragma unroll
    for (int mi = 0; mi < 4; ++mi)
#pragma unroll
      for (int nj = 0; nj < 2; ++nj)
        acc[0][mi][2 + nj] = __builtin_amdgcn_mfma_f32_16x16x32_bf16(a[mi], b[nj], acc[0][mi][2 + nj], 0, 0, 0);
    __builtin_amdgcn_s_setprio(0);
    __builtin_amdgcn_s_barrier();

    // ===== p2: (qm=1, qn=1) — reuse b; 4 A reads; NO stage =====
#pragma unroll
    for (int mi = 0; mi < 4; ++mi)
      a[mi] = *(const s16x8*)(Abase + 4096 + mi * 1024 + aRow);
    __builtin_amdgcn_s_barrier();
    asm volatile("s_waitcnt lgkmcnt(0)" ::: "memory");
    __builtin_amdgcn_s_setprio(1);
#pragma unroll
    for (int mi = 0; mi < 4; ++mi)
#pragma unroll
      for (int nj = 0; nj < 2; ++nj)
        acc[1][mi][2 + nj] = __builtin_amdgcn_mfma_f32_16x16x32_bf16(a[mi], b[nj], acc[1][mi][2 + nj], 0, 0, 0);
    __builtin_amdgcn_s_setprio(0);
    __builtin_amdgcn_s_barrier();

    // ===== p3: (qm=1, qn=0) — reuse a; 2 B reads; stage A(t+2) h0,h1 -> buf =====
#pragma unroll
    for (int nj = 0; nj < 2; ++nj)
      b[nj] = *(const s16x8*)(Bbase + nj * 1024 + bRow);
    stageA(t + 2, buf, 0);
    stageA(t + 2, buf, 1);
    asm volatile("s_waitcnt vmcnt(2)" ::: "memory");   // only A(t+2)x2 in flight; B(t+1) landed
    __builtin_amdgcn_s_barrier();
    asm volatile("s_waitcnt lgkmcnt(0)" ::: "memory");
    __builtin_amdgcn_s_setprio(1);
#pragma unroll
    for (int mi = 0; mi < 4; ++mi)
#pragma unroll
      for (int nj = 0; nj < 2; ++nj)
        acc[1][mi][nj] = __builtin_amdgcn_mfma_f32_16x16x32_bf16(a[mi], b[nj], acc[1][mi][nj], 0, 0, 0);
    __builtin_amdgcn_s_setprio(0);
    __builtin_amdgcn_s_barrier();
  }

  asm volatile("s_waitcnt vmcnt(0)" ::: "memory");   // drain clamped tail prefetches

  // ---- epilogue: bias + fast GELU, fp32 store (16x16 C/D mapping, m89/m91) ----
  float bcol[4];
#pragma unroll
  for (int ni = 0; ni < 4; ++ni)
    bcol[ni] = bias[col0 + (wni << 6) + ni * 16 + fr];

#pragma unroll
  for (int qm = 0; qm < 2; ++qm)
#pragma unroll
    for (int mi = 0; mi < 4; ++mi)
#pragma unroll
      for (int ni = 0; ni < 4; ++ni) {
        const int c = col0 + (wni << 6) + ni * 16 + fr;
#pragma unroll
        for (int j = 0; j < 4; ++j) {
          const int r = row0 + wmi * 128 + qm * 64 + mi * 16 + hi * 4 + j;
          float y = acc[qm][mi][ni][j] + bcol[ni];
          out[(size_t)r * HIDDEN + c] = fast_gelu(y);
        }
      }
}

extern "C" void kernel_launch(void* const* d_in, const int* in_sizes, int n_in,
                              void* d_out, int out_size, void* d_ws, size_t ws_size,
                              hipStream_t stream) {
  const float* x     = (const float*)d_in[0];
  const float* gamma = (const float*)d_in[1];
  const float* beta  = (const float*)d_in[2];
  const float* W     = (const float*)d_in[3];
  const float* bias  = (const float*)d_in[4];
  float* out = (float*)d_out;

  unsigned short* xn = (unsigned short*)d_ws;
  unsigned short* wb = (unsigned short*)((char*)d_ws + (size_t)TOKENS * HIDDEN * 2);

  hipLaunchKernelGGL(wconv_kernel, dim3(1024), dim3(256), 0, stream, W, wb);
  hipLaunchKernelGGL(ln_kernel, dim3(TOKENS), dim3(256), 0, stream, x, gamma, beta, xn);
  hipLaunchKernelGGL(gemm_kernel, dim3((TOKENS / BM) * (HIDDEN / BN)), dim3(512), 0, stream,
                     xn, wb, bias, out);
}